// Round 5
// baseline (680.269 us; speedup 1.0000x reference)
//
#include <hip/hip_runtime.h>
#include <math.h>

#define BB 16
#define TT 2048
#define DD 1024
#define THRESH 0.95f
#define RPB 8   // output rows per gather block (TT/RPB = 256 chunks per batch)

typedef float nt4 __attribute__((ext_vector_type(4)));

__device__ __forceinline__ void nt_store4(const float4& v, float4* p) {
    nt4 x = {v.x, v.y, v.z, v.w};
    __builtin_nontemporal_store(x, (nt4*)p);
}

// Serial integrate-and-fire over one 64-step group held in RREG (one alpha
// per lane). Chain is bit-identical to the reference. Lane j captures step
// j's cur value; lane GIDX accumulates the group's fire mask. cur is stored
// SIGN-TAGGED (sign bit = fire flag; cur is provably >= 0).
#define SCAN_GROUP(RREG, GIDX)                                                \
    {                                                                         \
        float cv = 0.f, pv = 0.f;                                             \
        _Pragma("unroll 16")                                                  \
        for (int j = 0; j < 64; ++j) {                                        \
            float a = __int_as_float(                                         \
                __builtin_amdgcn_readlane(__float_as_int(RREG), j));          \
            float pre  = integ + a;              /* chain: v_add */           \
            bool  fire = pre > THRESH;           /* chain: v_cmp */           \
            float c    = fire ? dist : a;                                     \
            integ      = fire ? pre - 1.f : pre; /* chain: v_cndmask */       \
            dist       = 1.f - integ;                                         \
            bool sel   = (lane == j);                                         \
            cv = sel ? c   : cv;                                              \
            pv = sel ? pre : pv;                                              \
        }                                                                     \
        bool myfire = pv > THRESH;                                            \
        cp[(GIDX) * 64 + lane] = myfire ? -cv : cv;   /* sign-tagged */       \
        unsigned long long bm = __ballot(myfire);                             \
        gmask = (lane == (GIDX)) ? bm : gmask;                                \
    }

// ---------------- Kernel 1: projection + (last-block) scan ----------------
// proj keeps its BW-optimal 8192-block shape. Each block releases its 4
// alphas (agent-scope stores), then bumps done_ctr[batch] with a device
// atomicAdd after __threadfence(). The 512th finisher for a batch runs that
// batch's serial scan in wave 0, reading alphas with agent-scope loads
// (coherent across non-coherent XCD L2s — G16). No spin, no ordering
// assumption: exactly one block observes old==511 and it does so after all
// alphas of its batch are globally visible.
__global__ __launch_bounds__(256) void proj_scan_kernel(
    const float* __restrict__ hs, const float* __restrict__ hs_mask,
    const float* __restrict__ w, const float* __restrict__ bias,
    float* __restrict__ alphas, float* __restrict__ cur,
    int* __restrict__ fire_times, float* __restrict__ out_mask,
    int* __restrict__ done_ctr)
{
    __shared__ int s_last;
    int row  = blockIdx.x * 4 + (threadIdx.x >> 6);   // b*T + t
    int lane = threadIdx.x & 63;
    int b    = blockIdx.x >> 9;                       // 512 blocks per batch

    // ---- projection: 4 rows per block, one wave per row ----
    {
        const float4* hp = (const float4*)(hs + (size_t)row * DD);
        const float4* wp = (const float4*)w;
        float sum = 0.f;
#pragma unroll
        for (int j = 0; j < 4; ++j) {
            float4 h4 = hp[lane + 64 * j];
            float4 w4 = wp[lane + 64 * j];
            sum += h4.x * w4.x + h4.y * w4.y + h4.z * w4.z + h4.w * w4.w;
        }
#pragma unroll
        for (int off = 32; off; off >>= 1) sum += __shfl_down(sum, off, 64);
        if (lane == 0) {
            float x  = sum + bias[0];
            float al = 1.f / (1.f + expf(-x));   // expf: fire decisions rounding-sensitive
            __hip_atomic_store(&alphas[row], al * hs_mask[row],
                               __ATOMIC_RELAXED, __HIP_MEMORY_SCOPE_AGENT);
        }
    }

    // ---- last-block-done handshake ----
    __syncthreads();
    if (threadIdx.x == 0) {
        __threadfence();                              // release: alpha stores drained
        int old = atomicAdd(&done_ctr[b], 1);         // device-scope
        s_last = (old == 511);
    }
    __syncthreads();
    if (!s_last || threadIdx.x >= 64) return;

    // ---- scan for batch b (wave 0 of the last finisher) ----
    const float* ap = alphas + (size_t)b * TT;
    float*       cp = cur    + (size_t)b * TT;

    unsigned long long gmask = 0ull;         // lane g: fire mask of steps [g*64,(g+1)*64)
    float integ = 0.f, dist = 1.f;
    double dsum = 0.0;

    for (int outer = 0; outer < 4; ++outer) {
        int base = outer * 512 + lane;
        // agent-scope loads: bypass stale per-XCD L2 lines
        float r0 = __hip_atomic_load(&ap[base +   0], __ATOMIC_RELAXED, __HIP_MEMORY_SCOPE_AGENT);
        float r1 = __hip_atomic_load(&ap[base +  64], __ATOMIC_RELAXED, __HIP_MEMORY_SCOPE_AGENT);
        float r2 = __hip_atomic_load(&ap[base + 128], __ATOMIC_RELAXED, __HIP_MEMORY_SCOPE_AGENT);
        float r3 = __hip_atomic_load(&ap[base + 192], __ATOMIC_RELAXED, __HIP_MEMORY_SCOPE_AGENT);
        float r4 = __hip_atomic_load(&ap[base + 256], __ATOMIC_RELAXED, __HIP_MEMORY_SCOPE_AGENT);
        float r5 = __hip_atomic_load(&ap[base + 320], __ATOMIC_RELAXED, __HIP_MEMORY_SCOPE_AGENT);
        float r6 = __hip_atomic_load(&ap[base + 384], __ATOMIC_RELAXED, __HIP_MEMORY_SCOPE_AGENT);
        float r7 = __hip_atomic_load(&ap[base + 448], __ATOMIC_RELAXED, __HIP_MEMORY_SCOPE_AGENT);
        dsum += (double)r0 + (double)r1 + (double)r2 + (double)r3
              + (double)r4 + (double)r5 + (double)r6 + (double)r7;
        int gb = outer * 8;
        SCAN_GROUP(r0, gb + 0)
        SCAN_GROUP(r1, gb + 1)
        SCAN_GROUP(r2, gb + 2)
        SCAN_GROUP(r3, gb + 3)
        SCAN_GROUP(r4, gb + 4)
        SCAN_GROUP(r5, gb + 5)
        SCAN_GROUP(r6, gb + 6)
        SCAN_GROUP(r7, gb + 7)
    }

    // len + out_mask (order-insensitive sum; round tolerance huge)
#pragma unroll
    for (int off = 32; off; off >>= 1) dsum += __shfl_down(dsum, off, 64);
    int len = __double2int_rn(dsum);
    len = __shfl(len, 0, 64);
    float* mp = out_mask + (size_t)b * TT;
#pragma unroll
    for (int j = 0; j < TT / 64; ++j)
        mp[j * 64 + lane] = ((j * 64 + lane) < len) ? 1.f : 0.f;

    // Expand fire masks -> fire_times (order-preserving prefix over 32 groups)
    int cnt  = __popcll(gmask);
    int pref = cnt;
#pragma unroll
    for (int off = 1; off < 64; off <<= 1) {
        int y = __shfl_up(pref, off, 64);
        if (lane >= off) pref += y;
    }
    int pos = pref - cnt;
    unsigned long long m = gmask;
    int baset = lane * 64;
    int* fp = fire_times + (size_t)b * TT;
    while (m) {
        int j = __ffsll(m) - 1;
        fp[pos++] = baset + j;
        m &= m - 1;
    }

    // Pad fire_times[nf..TT) with the last fire time (0 if none) so gather
    // can load ft[r0+RPB-1] / ft[r0-1] unconditionally over poisoned ws.
    int nf = __shfl(pref, 63, 64);
    int lastf = 0;
    if (nf > 0) lastf = fp[nf - 1];          // uniform-address broadcast load
    for (int r = nf + lane; r < TT; r += 64) fp[r] = lastf;
}

// ---------------- Kernel 2: counted-stream gather (unchanged from R4) ----------------
__global__ __launch_bounds__(256) void gather_kernel(
    const float* __restrict__ hs, const float* __restrict__ alphas,
    const float* __restrict__ cur, const int* __restrict__ fire_times,
    float* __restrict__ out)
{
    int chunk = blockIdx.x;          // b * (TT/RPB) + c
    int b  = chunk >> 8;             // TT/RPB = 256
    int r0 = (chunk & 255) * RPB;
    int ti = threadIdx.x;            // 0..255, covers D via float4

    const int*    ft  = fire_times + (size_t)b * TT;
    const float*  al  = alphas     + (size_t)b * TT;
    const float*  cu  = cur        + (size_t)b * TT;
    const float4* hsb = (const float4*)(hs + (size_t)b * TT * DD);
    float4*       ob  = (float4*)(out + ((size_t)b * TT + r0) * DD);

    int t1 = ft[r0 + RPB - 1];       // padded -> always valid
    int t;
    float4 acc = {0.f, 0.f, 0.f, 0.f};
    if (r0 == 0) {
        t = 0;
    } else {
        int   tp = ft[r0 - 1];       // boundary frame (last fire of prev row)
        float cr = cu[tp];
        float wb = al[tp] - fabsf(cr);
        float4 h = hsb[(size_t)tp * 256 + ti];
        acc.x = wb * h.x; acc.y = wb * h.y;   // boundary term FIRST (reference order)
        acc.z = wb * h.z; acc.w = wb * h.w;
        t = tp + 1;
    }

    int emitted = 0;
#pragma unroll 2
    for (; t <= t1; ++t) {
        float  cr = cu[t];           // broadcast scalar; sign bit = fire flag
        float4 h  = hsb[(size_t)t * 256 + ti];
        float  cw = fabsf(cr);
        acc.x += cw * h.x; acc.y += cw * h.y;
        acc.z += cw * h.z; acc.w += cw * h.w;
        if (cr < 0.f) {              // fire: close this row (wave-uniform branch)
            nt_store4(acc, &ob[(size_t)emitted * 256 + ti]);
            float wb = al[t] - cw;   // reseed with boundary term for next row
            acc.x = wb * h.x; acc.y = wb * h.y;
            acc.z = wb * h.z; acc.w = wb * h.w;
            ++emitted;
        }
    }

    // Rows past the last fire stay zero.
    float4 z = {0.f, 0.f, 0.f, 0.f};
    for (int i = emitted; i < RPB; ++i)
        nt_store4(z, &ob[(size_t)i * 256 + ti]);
}

extern "C" void kernel_launch(void* const* d_in, const int* in_sizes, int n_in,
                              void* d_out, int out_size, void* d_ws, size_t ws_size,
                              hipStream_t stream) {
    const float* hs      = (const float*)d_in[0];   // [B,T,D]
    const float* hs_mask = (const float*)d_in[1];   // [B,1,T]
    const float* w       = (const float*)d_in[2];   // [D]
    const float* bias    = (const float*)d_in[3];   // scalar

    float* out      = (float*)d_out;                       // [B,T,D]
    float* out_mask = out + (size_t)BB * TT * DD;          // [B,1,T] as 0/1 floats

    float* alphas     = (float*)d_ws;                      // B*T floats
    float* cur        = alphas + BB * TT;                  // B*T floats (sign-tagged)
    int*   fire_times = (int*)(cur + BB * TT);             // B*T ints (padded)
    int*   done_ctr   = fire_times + BB * TT;              // B ints (must start at 0)

    hipMemsetAsync(done_ctr, 0, BB * sizeof(int), stream); // 64 B, graph-capturable

    proj_scan_kernel<<<BB * TT / 4, 256, 0, stream>>>(hs, hs_mask, w, bias,
                                                      alphas, cur, fire_times,
                                                      out_mask, done_ctr);
    gather_kernel<<<BB * (TT / RPB), 256, 0, stream>>>(hs, alphas, cur,
                                                       fire_times, out);
}

// Round 6
// 302.059 us; speedup vs baseline: 2.2521x; 2.2521x over previous
//
#include <hip/hip_runtime.h>
#include <math.h>

#define BB 16
#define TT 2048
#define DD 1024
#define THRESH 0.95f
#define RPB 16  // output rows per gather block (TT/RPB = 128 chunks per batch)

typedef float nt4 __attribute__((ext_vector_type(4)));

__device__ __forceinline__ void nt_store4(const float4& v, float4* p) {
    nt4 x = {v.x, v.y, v.z, v.w};
    __builtin_nontemporal_store(x, (nt4*)p);
}

// ---------------- Kernel 1: projection + sigmoid + mask ----------------
__global__ __launch_bounds__(256) void proj_kernel(
    const float* __restrict__ hs, const float* __restrict__ hs_mask,
    const float* __restrict__ w, const float* __restrict__ bias,
    float* __restrict__ alphas)
{
    int row  = blockIdx.x * 4 + (threadIdx.x >> 6);   // b*T + t
    int lane = threadIdx.x & 63;
    const float4* hp = (const float4*)(hs + (size_t)row * DD);
    const float4* wp = (const float4*)w;
    float sum = 0.f;
#pragma unroll
    for (int j = 0; j < 4; ++j) {
        float4 h4 = hp[lane + 64 * j];
        float4 w4 = wp[lane + 64 * j];
        sum += h4.x * w4.x + h4.y * w4.y + h4.z * w4.z + h4.w * w4.w;
    }
#pragma unroll
    for (int off = 32; off; off >>= 1) sum += __shfl_down(sum, off, 64);
    if (lane == 0) {
        float x  = sum + bias[0];
        float al = 1.f / (1.f + expf(-x));   // expf: fire decisions are rounding-sensitive
        alphas[row] = al * hs_mask[row];
    }
}

// ---------------- Kernel 2: integrate-and-fire scan (serial-exact) ----------------
// One wave per batch. Serial fp32 chain bit-identical to the reference.
// cur[t] is stored SIGN-TAGGED: sign bit = fire flag (cur is provably >= 0).
// fire_times[nf..TT) is PADDED with the last fire time so gather can load
// its chunk's end time unconditionally (known trip count -> counted stream).

#define SCAN_GROUP(RREG, GIDX)                                                \
    {                                                                         \
        float cv = 0.f, pv = 0.f;                                             \
        _Pragma("unroll 16")                                                  \
        for (int j = 0; j < 64; ++j) {                                        \
            float a = __int_as_float(                                         \
                __builtin_amdgcn_readlane(__float_as_int(RREG), j));          \
            float pre  = integ + a;              /* chain: v_add */           \
            bool  fire = pre > THRESH;           /* chain: v_cmp */           \
            float c    = fire ? dist : a;                                     \
            integ      = fire ? pre - 1.f : pre; /* chain: v_cndmask */       \
            dist       = 1.f - integ;                                         \
            bool sel   = (lane == j);                                         \
            cv = sel ? c   : cv;                                              \
            pv = sel ? pre : pv;                                              \
        }                                                                     \
        bool myfire = pv > THRESH;                                            \
        cp[(GIDX) * 64 + lane] = myfire ? -cv : cv;   /* sign-tagged */       \
        unsigned long long bm = __ballot(myfire);                             \
        gmask = (lane == (GIDX)) ? bm : gmask;                                \
    }

__global__ __launch_bounds__(64) void scan_kernel(
    const float* __restrict__ alphas, float* __restrict__ cur,
    int* __restrict__ fire_times, float* __restrict__ out_mask)
{
    int b    = blockIdx.x;
    int lane = threadIdx.x;                  // 0..63, one wave
    const float* ap = alphas + (size_t)b * TT;
    float*       cp = cur    + (size_t)b * TT;

    unsigned long long gmask = 0ull;         // lane g: fire mask of steps [g*64,(g+1)*64)
    float integ = 0.f, dist = 1.f;
    double dsum = 0.0;

    for (int outer = 0; outer < 4; ++outer) {
        int base = outer * 512 + lane;
        float r0 = ap[base +   0];
        float r1 = ap[base +  64];
        float r2 = ap[base + 128];
        float r3 = ap[base + 192];
        float r4 = ap[base + 256];
        float r5 = ap[base + 320];
        float r6 = ap[base + 384];
        float r7 = ap[base + 448];
        dsum += (double)r0 + (double)r1 + (double)r2 + (double)r3
              + (double)r4 + (double)r5 + (double)r6 + (double)r7;
        int gb = outer * 8;
        SCAN_GROUP(r0, gb + 0)
        SCAN_GROUP(r1, gb + 1)
        SCAN_GROUP(r2, gb + 2)
        SCAN_GROUP(r3, gb + 3)
        SCAN_GROUP(r4, gb + 4)
        SCAN_GROUP(r5, gb + 5)
        SCAN_GROUP(r6, gb + 6)
        SCAN_GROUP(r7, gb + 7)
    }

    // len + out_mask (order-insensitive sum; round tolerance huge)
#pragma unroll
    for (int off = 32; off; off >>= 1) dsum += __shfl_down(dsum, off, 64);
    int len = __double2int_rn(dsum);
    len = __shfl(len, 0, 64);
    float* mp = out_mask + (size_t)b * TT;
#pragma unroll
    for (int j = 0; j < TT / 64; ++j)
        mp[j * 64 + lane] = ((j * 64 + lane) < len) ? 1.f : 0.f;

    // Expand fire masks -> fire_times (order-preserving prefix over 32 groups)
    int cnt  = __popcll(gmask);
    int pref = cnt;
#pragma unroll
    for (int off = 1; off < 64; off <<= 1) {
        int y = __shfl_up(pref, off, 64);
        if (lane >= off) pref += y;
    }
    int pos = pref - cnt;
    unsigned long long m = gmask;
    int baset = lane * 64;
    int* fp = fire_times + (size_t)b * TT;
    while (m) {
        int j = __ffsll(m) - 1;
        fp[pos++] = baset + j;
        m &= m - 1;
    }

    // Pad fire_times[nf..TT) with the last fire time (0 if none).
    int nf = __shfl(pref, 63, 64);
    int lastf = 0;
    if (nf > 0) lastf = fp[nf - 1];          // uniform-address broadcast load
    for (int r = nf + lane; r < TT; r += 64) fp[r] = lastf;
}

// ---------------- Kernel 3: counted-stream gather, software-pipelined ----------------
// One block owns RPB consecutive output rows. Frame range [t0, t1] known
// upfront (t1 = ft[r0+RPB-1], padded). 2-stage pipeline: frame t+1's loads
// (index clamped to t1 -> no OOB) are issued before frame t is consumed, so
// L3 latency hides under the FMA + fire branch. Fire flag = sign bit of the
// broadcast cur[t] (wave-uniform branch, zero divergence). Accumulation
// order per row (boundary term first, then ascending t) matches reference.
__global__ __launch_bounds__(256) void gather_kernel(
    const float* __restrict__ hs, const float* __restrict__ alphas,
    const float* __restrict__ cur, const int* __restrict__ fire_times,
    float* __restrict__ out)
{
    int chunk = blockIdx.x;              // b * (TT/RPB) + c
    int b  = chunk >> 7;                 // TT/RPB = 128
    int r0 = (chunk & 127) * RPB;
    int ti = threadIdx.x;                // 0..255, covers D via float4

    const int*    ft  = fire_times + (size_t)b * TT;
    const float*  al  = alphas     + (size_t)b * TT;
    const float*  cu  = cur        + (size_t)b * TT;
    const float4* hsb = (const float4*)(hs + (size_t)b * TT * DD);
    float4*       ob  = (float4*)(out + ((size_t)b * TT + r0) * DD);

    int t1 = ft[r0 + RPB - 1];           // padded -> always valid
    int t;
    float4 acc = {0.f, 0.f, 0.f, 0.f};
    if (r0 == 0) {
        t = 0;
    } else {
        int   tp = ft[r0 - 1];           // boundary frame (last fire of prev row)
        float cr0 = cu[tp];
        float wb  = al[tp] - fabsf(cr0);
        float4 h0 = hsb[(size_t)tp * 256 + ti];
        acc.x = wb * h0.x; acc.y = wb * h0.y;  // boundary term FIRST (reference order)
        acc.z = wb * h0.z; acc.w = wb * h0.w;
        t = tp + 1;                      // may be > t1 (fully-drained chunk)
    }

    // Stage-0 preload (clamped so empty-range chunks don't read OOB).
    int   tpre = (t <= t1) ? t : t1;
    float  cr = cu[tpre];
    float4 h  = hsb[(size_t)tpre * 256 + ti];

    int emitted = 0;
    for (; t <= t1; ++t) {
        int tn = (t < t1) ? t + 1 : t1;  // clamped next (uniform -> SALU select)
        float  cr_n = cu[tn];            // prefetch next frame's weight + data
        float4 h_n  = hsb[(size_t)tn * 256 + ti];

        float cw = fabsf(cr);
        acc.x += cw * h.x; acc.y += cw * h.y;
        acc.z += cw * h.z; acc.w += cw * h.w;
        if (cr < 0.f) {                  // fire: close this row (wave-uniform)
            nt_store4(acc, &ob[(size_t)emitted * 256 + ti]);
            float wb = al[t] - cw;       // reseed with boundary term for next row
            acc.x = wb * h.x; acc.y = wb * h.y;
            acc.z = wb * h.z; acc.w = wb * h.w;
            ++emitted;
        }
        cr = cr_n; h = h_n;
    }

    // Rows past the last fire stay zero.
    float4 z = {0.f, 0.f, 0.f, 0.f};
    for (int i = emitted; i < RPB; ++i)
        nt_store4(z, &ob[(size_t)i * 256 + ti]);
}

extern "C" void kernel_launch(void* const* d_in, const int* in_sizes, int n_in,
                              void* d_out, int out_size, void* d_ws, size_t ws_size,
                              hipStream_t stream) {
    const float* hs      = (const float*)d_in[0];   // [B,T,D]
    const float* hs_mask = (const float*)d_in[1];   // [B,1,T]
    const float* w       = (const float*)d_in[2];   // [D]
    const float* bias    = (const float*)d_in[3];   // scalar

    float* out      = (float*)d_out;                       // [B,T,D]
    float* out_mask = out + (size_t)BB * TT * DD;          // [B,1,T] as 0/1 floats

    float* alphas     = (float*)d_ws;                      // B*T floats
    float* cur        = alphas + BB * TT;                  // B*T floats (sign-tagged)
    int*   fire_times = (int*)(cur + BB * TT);             // B*T ints (padded)

    proj_kernel<<<BB * TT / 4, 256, 0, stream>>>(hs, hs_mask, w, bias, alphas);
    scan_kernel<<<BB, 64, 0, stream>>>(alphas, cur, fire_times, out_mask);
    gather_kernel<<<BB * (TT / RPB), 256, 0, stream>>>(hs, alphas, cur,
                                                       fire_times, out);
}